// Round 5
// baseline (264.315 us; speedup 1.0000x reference)
//
#include <hip/hip_runtime.h>
#include <stdint.h>

#define D 128
#define RNUM 4
#define TM 32          // nodes per GEMM tile

typedef unsigned short u16;
typedef __attribute__((ext_vector_type(8))) short short8;
typedef __attribute__((ext_vector_type(4))) float floatx4;

__device__ inline u16 f2bf(float f) {
  union { float f; uint32_t u; } c; c.f = f;
  uint32_t r = (c.u + 0x7FFFu + ((c.u >> 16) & 1u)) >> 16;
  return (u16)r;
}
__device__ inline uint32_t pack2(float a, float b) {
  return (uint32_t)f2bf(a) | ((uint32_t)f2bf(b) << 16);
}
__device__ inline float bflo(uint32_t w) {
  union { uint32_t u; float f; } c; c.u = w << 16; return c.f;
}
__device__ inline float bfhi(uint32_t w) {
  union { uint32_t u; float f; } c; c.u = w & 0xFFFF0000u; return c.f;
}

__device__ inline float fast_tanh(float v) {
  float a = fabsf(v);
  float e = __builtin_amdgcn_exp2f(a * 2.8853900817779268f);  // e^(2a)
  float t = 1.0f - 2.0f * __builtin_amdgcn_rcpf(e + 1.0f);
  return copysignf(t, v);
}

// Build Wt[r][col][k] (bf16) + bias; also zero counts (grid-stride).
__global__ void prep_kernel(const float* __restrict__ W_rel, const float* __restrict__ b_rel,
                            const float* __restrict__ W_root, const float* __restrict__ b_root,
                            u16* __restrict__ Wt, float* __restrict__ bias,
                            uint32_t* __restrict__ counts, int nseg) {
  int idx = blockIdx.x * 256 + threadIdx.x;
  for (int i = idx; i < nseg; i += RNUM * D * 2 * D) counts[i] = 0u;
  if (idx < RNUM * D) bias[idx] = b_rel[idx] + b_root[idx];
  if (idx >= RNUM * D * 2 * D) return;
  int k   = idx & 255;
  int col = (idx >> 8) & 127;
  int r   = idx >> 15;
  float v = (k < D) ? W_rel[((size_t)r * D + k) * D + col]
                    : W_root[((size_t)r * D + (k - D)) * D + col];
  Wt[idx] = f2bf(v);
}

// x (f32) -> x16 (bf16), 8 dims per thread
__global__ void xcvt_kernel(const float* __restrict__ x, u16* __restrict__ x16, int total8) {
  int t = blockIdx.x * 256 + threadIdx.x;
  if (t >= total8) return;
  const float4* s = (const float4*)(x + (size_t)t * 8);
  float4 lo = s[0], hi = s[1];
  uint4 pk;
  pk.x = pack2(lo.x, lo.y); pk.y = pack2(lo.z, lo.w);
  pk.z = pack2(hi.x, hi.y); pk.w = pack2(hi.z, hi.w);
  *(uint4*)(x16 + (size_t)t * 8) = pk;
}

// counts[dst*4 + rel]++
__global__ void hist_kernel(const int* __restrict__ ei, const int* __restrict__ ea,
                            uint32_t* __restrict__ counts, int E) {
  int t = blockIdx.x * 256 + threadIdx.x;
  if (t >= E) return;
  atomicAdd(&counts[ei[E + t] * 4 + ea[t]], 1u);
}

// Hierarchical exclusive scan, 16 items/thread.
__global__ __launch_bounds__(1024) void scan1_kernel(const uint32_t* __restrict__ counts,
                                                     uint32_t* __restrict__ offsets,
                                                     uint32_t* __restrict__ bsums, int n) {
  __shared__ uint32_t sums[1024];
  int t = threadIdx.x;
  int base = blockIdx.x * 16384 + t * 16;
  uint32_t loc[16];
  uint32_t s = 0;
#pragma unroll
  for (int i = 0; i < 16; ++i) {
    int idx = base + i;
    uint32_t c = (idx < n) ? counts[idx] : 0u;
    loc[i] = s;
    s += c;
  }
  sums[t] = s;
  __syncthreads();
  for (int off = 1; off < 1024; off <<= 1) {
    uint32_t v = (t >= off) ? sums[t - off] : 0u;
    __syncthreads();
    sums[t] += v;
    __syncthreads();
  }
  uint32_t be = (t == 0) ? 0u : sums[t - 1];
#pragma unroll
  for (int i = 0; i < 16; ++i) {
    int idx = base + i;
    if (idx < n) offsets[idx] = be + loc[i];
  }
  if (t == 1023) bsums[blockIdx.x] = sums[1023];
}

__global__ __launch_bounds__(512) void scan2_kernel(uint32_t* __restrict__ bsums, int nb) {
  __shared__ uint32_t s[512];
  int t = threadIdx.x;
  uint32_t c = (t < nb) ? bsums[t] : 0u;
  s[t] = c;
  __syncthreads();
  for (int off = 1; off < 512; off <<= 1) {
    uint32_t v = (t >= off) ? s[t - off] : 0u;
    __syncthreads();
    s[t] += v;
    __syncthreads();
  }
  if (t < nb) bsums[t] = s[t] - c;
}

__global__ __launch_bounds__(1024) void scan3_kernel(uint32_t* __restrict__ offsets,
                                                     uint32_t* __restrict__ cursor,
                                                     const uint32_t* __restrict__ bsums,
                                                     int n, int total) {
  int t = threadIdx.x;
  int base = blockIdx.x * 16384 + t * 16;
  uint32_t add = bsums[blockIdx.x];
#pragma unroll
  for (int i = 0; i < 16; ++i) {
    int idx = base + i;
    if (idx < n) {
      uint32_t v = offsets[idx] + add;
      offsets[idx] = v;
      cursor[idx] = v;
    }
  }
  if (base == 0) offsets[n] = (uint32_t)total;
}

// recs[pos] = src, bucketed by (dst*4 + rel)
__global__ void fill_kernel(const int* __restrict__ ei, const int* __restrict__ ea,
                            uint32_t* __restrict__ cursor, uint32_t* __restrict__ recs, int E) {
  int t = blockIdx.x * 256 + threadIdx.x;
  if (t >= E) return;
  uint32_t pos = atomicAdd(&cursor[ei[E + t] * 4 + ea[t]], 1u);
  recs[pos] = (uint32_t)ei[t];
}

// Fused gather (bf16 rows, register accumulate) -> swizzled bf16 LDS -> MFMA GEMM + tanh.
// 512 threads = 8 waves. Wave w owns 16 contiguous (node,rel) rows: node = w*4 + (t>>2),
// rel = t&3. Lane l accumulates dims (2l, 2l+1) in f32 registers.
__global__ __launch_bounds__(512, 8) void fused_kernel(
    const u16* __restrict__ x16, const uint32_t* __restrict__ recs,
    const uint32_t* __restrict__ offsets,
    const u16* __restrict__ Wt, const float* __restrict__ bias,
    float* __restrict__ out, int N) {
  __shared__ __align__(16) u16 sA[5 * TM * D];   // 40 KB

  const int tid = threadIdx.x;
  const int w = tid >> 6, l = tid & 63;
  const int nodeBase = blockIdx.x * TM;

  // ---- stage x slot: copy bf16 row chunks, swizzled ----
  {
    int c = tid & 15, node = tid >> 4;
    int gnode = nodeBase + node;
    uint4 pk = {0u, 0u, 0u, 0u};
    if (gnode < N) pk = *(const uint4*)(x16 + (size_t)gnode * D + c * 8);
    *(uint4*)&sA[4 * (TM * D) + node * D + ((c ^ (node & 7)) << 3)] = pk;
  }

  // ---- gather: wave walks its contiguous edge range, register accumulate, flush per row ----
  {
    const uint32_t* op = offsets + ((size_t)blockIdx.x * (TM * 4) + w * 16);
    uint32_t e  = (uint32_t)__builtin_amdgcn_readfirstlane((int)op[0]);
    uint32_t eE = (uint32_t)__builtin_amdgcn_readfirstlane((int)op[16]);
    int tr = 0;
    uint32_t bnd = (uint32_t)__builtin_amdgcn_readfirstlane((int)op[1]);
    float ax = 0.f, ay = 0.f;
    const int ch = l >> 2, q2 = (l & 3) * 2;

#define FLUSH_ROW do {                                                         \
      int node_ = w * 4 + (tr >> 2); int rel_ = tr & 3;                        \
      int idx_ = rel_ * (TM * D) + node_ * D + ((ch ^ (node_ & 7)) << 3) + q2; \
      *(uint32_t*)&sA[idx_] = pack2(ax, ay);                                   \
      ax = 0.f; ay = 0.f; ++tr;                                                \
      bnd = (tr < 16) ? (uint32_t)__builtin_amdgcn_readfirstlane((int)op[tr + 1]) \
                      : 0xFFFFFFFFu;                                           \
    } while (0)

    for (; e + 8 <= eE; e += 8) {
      uint32_t rc[8];
#pragma unroll
      for (int j = 0; j < 8; ++j) rc[j] = recs[e + j];
      uint32_t wv[8];
#pragma unroll
      for (int j = 0; j < 8; ++j)
        wv[j] = *(const uint32_t*)(x16 + (size_t)rc[j] * D + 2 * l);
#pragma unroll
      for (int j = 0; j < 8; ++j) {
        while (e + j >= bnd) FLUSH_ROW;
        ax += bflo(wv[j]); ay += bfhi(wv[j]);
      }
    }
    if (e + 4 <= eE) {
      uint32_t rc[4];
#pragma unroll
      for (int j = 0; j < 4; ++j) rc[j] = recs[e + j];
      uint32_t wv[4];
#pragma unroll
      for (int j = 0; j < 4; ++j)
        wv[j] = *(const uint32_t*)(x16 + (size_t)rc[j] * D + 2 * l);
#pragma unroll
      for (int j = 0; j < 4; ++j) {
        while (e + j >= bnd) FLUSH_ROW;
        ax += bflo(wv[j]); ay += bfhi(wv[j]);
      }
      e += 4;
    }
    for (; e < eE; ++e) {
      while (e >= bnd) FLUSH_ROW;
      uint32_t wv0 = *(const uint32_t*)(x16 + (size_t)recs[e] * D + 2 * l);
      ax += bflo(wv0); ay += bfhi(wv0);
    }
    while (tr < 16) FLUSH_ROW;
#undef FLUSH_ROW
  }
  __syncthreads();

  // ---- MFMA phase: wave w -> cols [w*16, w*16+16) ----
  const int lrow = l & 15, lhi = l >> 4;
  floatx4 oacc[2];
  oacc[0] = (floatx4){0.f, 0.f, 0.f, 0.f};
  oacc[1] = (floatx4){0.f, 0.f, 0.f, 0.f};

  for (int r = 0; r < RNUM; ++r) {
    floatx4 acc[2];
    acc[0] = (floatx4){0.f, 0.f, 0.f, 0.f};
    acc[1] = (floatx4){0.f, 0.f, 0.f, 0.f};

#pragma unroll
    for (int ks = 0; ks < 8; ++ks) {
      const u16* Abase = (ks < 4) ? (sA + r * (TM * D)) : (sA + 4 * (TM * D));
      const int cRead = (ks & 3) * 4 + lhi;
      short8 afr[2];
#pragma unroll
      for (int m = 0; m < 2; ++m) {
        int node = m * 16 + lrow;
        afr[m] = *(const short8*)&Abase[node * D + ((cRead ^ (node & 7)) << 3)];
      }
      int col = w * 16 + lrow;
      short8 bfr = *(const short8*)(Wt + ((size_t)(r * D + col) * (2 * D) + ks * 32 + lhi * 8));
#pragma unroll
      for (int m = 0; m < 2; ++m)
        acc[m] = __builtin_amdgcn_mfma_f32_16x16x32_bf16(afr[m], bfr, acc[m], 0, 0, 0);
    }

    float bb = bias[r * D + w * 16 + lrow];
#pragma unroll
    for (int m = 0; m < 2; ++m)
#pragma unroll
      for (int j = 0; j < 4; ++j)
        oacc[m][j] += fast_tanh(acc[m][j] + bb);
  }

  // ---- store: C row = lhi*4 + j, col = lane&15 ----
#pragma unroll
  for (int m = 0; m < 2; ++m) {
#pragma unroll
    for (int j = 0; j < 4; ++j) {
      int node = nodeBase + m * 16 + lhi * 4 + j;
      if (node < N) out[(size_t)node * D + w * 16 + lrow] = oacc[m][j];
    }
  }
}

extern "C" void kernel_launch(void* const* d_in, const int* in_sizes, int n_in,
                              void* d_out, int out_size, void* d_ws, size_t ws_size,
                              hipStream_t stream) {
  const float* x      = (const float*)d_in[0];
  const int*   ei     = (const int*)d_in[1];
  const int*   ea     = (const int*)d_in[2];
  const float* W_rel  = (const float*)d_in[3];
  const float* b_rel  = (const float*)d_in[4];
  const float* W_root = (const float*)d_in[5];
  const float* b_root = (const float*)d_in[6];
  float* out = (float*)d_out;

  const int N = in_sizes[0] / D;          // 100000
  const int E = in_sizes[2];              // 640000
  const int NB = (N + TM - 1) / TM;       // 3125 tiles
  const int NSEG = N * RNUM;              // 400000 (node, rel) segments
  const int NBLK = (NSEG + 16383) / 16384;  // 25

  // ws layout (256B-aligned regions)
  size_t o = 0;
  auto nxt = [&](size_t bytes) { size_t p = o; o += (bytes + 255) & ~(size_t)255; return p; };
  u16*      Wt      = (u16*)((char*)d_ws + nxt((size_t)RNUM * D * 2 * D * 2));
  float*    bias    = (float*)((char*)d_ws + nxt((size_t)RNUM * D * 4));
  uint32_t* counts  = (uint32_t*)((char*)d_ws + nxt((size_t)NSEG * 4));
  uint32_t* offsets = (uint32_t*)((char*)d_ws + nxt((size_t)(NSEG + 1) * 4));
  uint32_t* cursor  = (uint32_t*)((char*)d_ws + nxt((size_t)NSEG * 4));
  uint32_t* bsums   = (uint32_t*)((char*)d_ws + nxt((size_t)NBLK * 4));
  uint32_t* recs    = (uint32_t*)((char*)d_ws + nxt((size_t)E * 4));
  u16*      x16     = (u16*)((char*)d_ws + nxt((size_t)N * D * 2));

  prep_kernel<<<(RNUM * D * 2 * D + 255) / 256, 256, 0, stream>>>(W_rel, b_rel, W_root, b_root,
                                                                  Wt, bias, counts, NSEG);
  xcvt_kernel<<<(N * (D / 8) + 255) / 256, 256, 0, stream>>>(x, x16, N * (D / 8));
  hist_kernel<<<(E + 255) / 256, 256, 0, stream>>>(ei, ea, counts, E);
  scan1_kernel<<<NBLK, 1024, 0, stream>>>(counts, offsets, bsums, NSEG);
  scan2_kernel<<<1, 512, 0, stream>>>(bsums, NBLK);
  scan3_kernel<<<NBLK, 1024, 0, stream>>>(offsets, cursor, bsums, NSEG, E);
  fill_kernel<<<(E + 255) / 256, 256, 0, stream>>>(ei, ea, cursor, recs, E);
  fused_kernel<<<NB, 512, 0, stream>>>(x16, recs, offsets, Wt, bias, out, N);
}